// Round 10
// baseline (342.810 us; speedup 1.0000x reference)
//
#include <hip/hip_runtime.h>
#include <float.h>
#include <math.h>

// SelfContextCluster: N=16, H=W=64, DIM=256, HEADS=8, HD=32, ANCH=8 (64 anchors)
// m = 128 maps (n*8+head). Channel layout of xp row (512): head*64 + c,
// c<32 = point, c>=32 = value.
//
// Structure (R9, validated): XP produced by TWO kernels split by consumer
// precision. Point cols: sequential-fmaf fp32 GEMM (argmax path needs
// fp32-class XP; MFMA split-bf16 flipped argmaxes in R7/R8). Value cols:
// 3-term split-bf16 MFMA (tolerant linear path, 25x margin).
// R10: dbuf proj_point (bit-identical math, 1 barrier/K-step), batched
// scatter loads (identical order), float2 pool (exact tree replication).

#define NPIX   4096     // 64*64
#define NIMG   16
#define TOTPIX 65536
#define DIM2   512

typedef __attribute__((ext_vector_type(8))) short bf16x8;
typedef __attribute__((ext_vector_type(4))) float f32x4;

// ---------------------------------------------------------------------------
// Kernel A1: point-channel fp32 GEMM. M=65536, Npt=256, K=256.
// BM=BN=128, BK=32, 512 threads, 8x4 micro-tile.
// R10: double-buffered LDS, ONE barrier per K-step. R5's dbuf spill was at
// acc=64+stage=32 (VGPR demand ~140); here acc=32+stage=16+frag=12 ~ 80 ->
// no spill (tripwire: WRITE_SIZE must stay 65.5MB). ds_writes for tile t+1
// overlap the FMA block of tile t; safety: writes at iter t hit buf^1 whose
// last read was iter t-1, fenced by that iter's single barrier.
// Same k order as R6/R9 -> bit-identical XP (argmax-safe).
// ---------------------------------------------------------------------------
#define BM 128
#define BN 128
#define BK 32

__global__ __launch_bounds__(512, 2) void proj_point(
    const float* __restrict__ X, const float* __restrict__ W,
    const float* __restrict__ bias, float* __restrict__ XP) {
  __shared__ float As[2][BK][BM];
  __shared__ float Bs[2][BK][BN];
  const int tid = threadIdx.x;
  const int M0 = blockIdx.x * BM, C0 = blockIdx.y * BN;   // C0: point-col space
  const int tm = tid >> 5, tn = tid & 31;      // 16 x 32 thread grid

  const int r = tid & 127;
  const int kq = (tid >> 7) << 3;              // 0,8,16,24

  const int pcr = C0 + r;                       // point-col of staged W row
  const float* Xa = X + (size_t)(M0 + r) * 256 + kq;
  const float* Wb = W + (size_t)((pcr >> 5) * 64 + (pcr & 31)) * 256 + kq;

  float4 xa0, xa1, wb0, wb1;

#define LOADT(ko)                                                      \
  do {                                                                 \
    xa0 = *(const float4*)(Xa + (ko));                                 \
    xa1 = *(const float4*)(Xa + (ko) + 4);                             \
    wb0 = *(const float4*)(Wb + (ko));                                 \
    wb1 = *(const float4*)(Wb + (ko) + 4);                             \
  } while (0)

#define WRITEB(bf)                                                     \
  do {                                                                 \
    _Pragma("unroll") for (int j = 0; j < 4; ++j) {                    \
      As[bf][kq + j][r]     = (&xa0.x)[j];                             \
      As[bf][kq + 4 + j][r] = (&xa1.x)[j];                             \
      Bs[bf][kq + j][r]     = (&wb0.x)[j];                             \
      Bs[bf][kq + 4 + j][r] = (&wb1.x)[j];                             \
    }                                                                  \
  } while (0)

  float acc[8][4];
#pragma unroll
  for (int i = 0; i < 8; ++i)
#pragma unroll
    for (int j = 0; j < 4; ++j) acc[i][j] = 0.f;

  LOADT(0);
  WRITEB(0);
  LOADT(BK);
  __syncthreads();

  for (int t = 0; t < 8; ++t) {
    const int cur = t & 1;
    if (t < 7) {
      WRITEB(cur ^ 1);                 // regs hold tile t+1
      if (t < 6) LOADT((t + 2) * BK);  // issue loads for tile t+2
    }
#pragma unroll
    for (int kk = 0; kk < BK; ++kk) {
      float a[8], b[4];
      *(float4*)&a[0] = *(const float4*)&As[cur][kk][tm * 8];
      *(float4*)&a[4] = *(const float4*)&As[cur][kk][tm * 8 + 4];
      *(float4*)&b[0] = *(const float4*)&Bs[cur][kk][tn * 4];
#pragma unroll
      for (int i = 0; i < 8; ++i)
#pragma unroll
        for (int j = 0; j < 4; ++j)
          acc[i][j] = fmaf(a[i], b[j], acc[i][j]);
    }
    __syncthreads();
  }

  // point-col c = C0 + tn*4 (4-aligned within a 32-chunk) -> phys contiguous
  const int c = C0 + tn * 4;
  const int pcol = (c >> 5) * 64 + (c & 31);
  const float4 bq = *(const float4*)(bias + pcol);
#pragma unroll
  for (int i = 0; i < 8; ++i) {
    const size_t row = (size_t)(M0 + tm * 8 + i) * DIM2 + pcol;
    float4 o;
    o.x = acc[i][0] + bq.x; o.y = acc[i][1] + bq.y;
    o.z = acc[i][2] + bq.z; o.w = acc[i][3] + bq.w;
    *(float4*)(XP + row) = o;
  }
}

// ---------------------------------------------------------------------------
// Kernel A2: value-channel 3-term split-bf16 MFMA GEMM (R9 verbatim).
// ---------------------------------------------------------------------------
__device__ __forceinline__ void split2(float x, unsigned short& h1,
                                       unsigned short& h2) {
  unsigned u1 = __float_as_uint(x);
  h1 = (unsigned short)(u1 >> 16);
  float r1 = x - __uint_as_float(u1 & 0xFFFF0000u);
  h2 = (unsigned short)(__float_as_uint(r1) >> 16);
}

__global__ __launch_bounds__(256, 2) void proj_value(
    const float* __restrict__ X, const float* __restrict__ W,
    const float* __restrict__ bias, float* __restrict__ XP) {
  __shared__ unsigned char lds[4 * 8192];   // A1,A2,B1,B2 planes
  const int tid = threadIdx.x;
  const int M0 = blockIdx.x * 128;
  const int V0 = blockIdx.y * 128;          // value-col space (0 or 128)

  const int w = tid >> 6, l = tid & 63;
  const int wm = w >> 1, wn = w & 1;

  const int jj = tid & 7;
  const int rsub = tid >> 3;

  const float* Xbase = X + (size_t)M0 * 256;

  float4 ra[4], rb[4];
#define GLOADV(kofs)                                                          \
  do {                                                                        \
    _Pragma("unroll") for (int i = 0; i < 4; ++i) {                           \
      ra[i] = *(const float4*)(Xbase + (size_t)(i * 32 + rsub) * 256 + (kofs) + jj * 4); \
      rb[i] = *(const float4*)(W + (size_t)((((V0 >> 5) + i) * 64) + 32 + rsub) * 256 + (kofs) + jj * 4); \
    }                                                                         \
  } while (0)

  f32x4 acc[4][4] = {};

  const int fr = l & 15, kg = l >> 4;
  const int chunk = kg << 4;                 // 16B chunk within 64B row

  GLOADV(0);

  for (int s = 0; s < 8; ++s) {
    __syncthreads();
#pragma unroll
    for (int i = 0; i < 4; ++i) {
      const int row = i * 32 + rsub;
      const int off = row * 64 + jj * 8;
      unsigned short a1[4], a2[4], b1[4], b2[4];
#pragma unroll
      for (int e = 0; e < 4; ++e) {
        split2(((const float*)&ra[i])[e], a1[e], a2[e]);
        split2(((const float*)&rb[i])[e], b1[e], b2[e]);
      }
#define PK2(arr) make_uint2((unsigned)(arr)[0] | ((unsigned)(arr)[1] << 16),  \
                            (unsigned)(arr)[2] | ((unsigned)(arr)[3] << 16))
      *(uint2*)(lds + 0 * 8192 + off) = PK2(a1);
      *(uint2*)(lds + 1 * 8192 + off) = PK2(a2);
      *(uint2*)(lds + 2 * 8192 + off) = PK2(b1);
      *(uint2*)(lds + 3 * 8192 + off) = PK2(b2);
#undef PK2
    }
    __syncthreads();
    if (s < 7) GLOADV((s + 1) * 32);

    bf16x8 af[4][2];
#pragma unroll
    for (int mi = 0; mi < 4; ++mi) {
      const int base = (wm * 64 + mi * 16 + fr) * 64 + chunk;
      af[mi][0] = *(const bf16x8*)(lds + 0 * 8192 + base);
      af[mi][1] = *(const bf16x8*)(lds + 1 * 8192 + base);
    }
#pragma unroll
    for (int ni = 0; ni < 4; ++ni) {
      const int base = (wn * 64 + ni * 16 + fr) * 64 + chunk;
      const bf16x8 b1 = *(const bf16x8*)(lds + 2 * 8192 + base);
      const bf16x8 b2 = *(const bf16x8*)(lds + 3 * 8192 + base);
#pragma unroll
      for (int mi = 0; mi < 4; ++mi) {
        f32x4 c = acc[mi][ni];
        c = __builtin_amdgcn_mfma_f32_16x16x32_bf16(af[mi][0], b1, c, 0, 0, 0);
        c = __builtin_amdgcn_mfma_f32_16x16x32_bf16(af[mi][0], b2, c, 0, 0, 0);
        c = __builtin_amdgcn_mfma_f32_16x16x32_bf16(af[mi][1], b1, c, 0, 0, 0);
        acc[mi][ni] = c;
      }
    }
  }

  // epilogue: value-col vc = V0 + wn*64 + ni*16 + fr -> phys col
  const int orow0 = M0 + wm * 64 + (l >> 4) * 4;
#pragma unroll
  for (int ni = 0; ni < 4; ++ni) {
    const int vc = V0 + wn * 64 + ni * 16 + fr;
    const int pcol = (vc >> 5) * 64 + 32 + (vc & 31);
    const float bv = bias[pcol];
#pragma unroll
    for (int mi = 0; mi < 4; ++mi)
#pragma unroll
      for (int j = 0; j < 4; ++j)
        XP[(size_t)(orow0 + mi * 16 + j) * DIM2 + pcol] = acc[mi][ni][j] + bv;
  }
}

// ---------------------------------------------------------------------------
// Kernel B: 8x8 max-pool + l2-normalize point1, store value1.
// R10: thread t handles channel PAIR (2t, 2t+1) via float2 loads (halves
// load-instruction count). Norm reduction reproduces the original 5-level
// butterfly BIT-EXACTLY: original levels xor16,8,4,2 on cc preserve channel
// parity (even offsets), so per-parity butterfly over lane o=8,4,2,1
// (== cc xor 16,8,4,2) then s0+s1 (== final cc xor 1 level). Max is
// order-invariant. Head h = t>>5; within 32-group, lanes<16 are point.
// ---------------------------------------------------------------------------
__global__ __launch_bounds__(256) void pool_norm(
    const float* __restrict__ XP, float* __restrict__ P1N,
    float* __restrict__ V1) {
  const int n = blockIdx.x, a = blockIdx.y;
  const int ay = a >> 3, ax = a & 7;
  const int tid = threadIdx.x;
  const size_t base = ((size_t)n * NPIX + (size_t)(ay * 8) * 64 + ax * 8) * DIM2;
  const int c0 = tid * 2;
  float m0 = -FLT_MAX, m1 = -FLT_MAX;
#pragma unroll
  for (int iy = 0; iy < 8; ++iy) {
    const float* rowp = XP + base + (size_t)iy * 64 * DIM2;
#pragma unroll
    for (int ix = 0; ix < 8; ++ix) {
      const float2 v = *(const float2*)(rowp + (size_t)ix * DIM2 + c0);
      m0 = fmaxf(m0, v.x);
      m1 = fmaxf(m1, v.y);
    }
  }
  const int m = n * 8 + (tid >> 5);
  const int l32 = tid & 31;
  float s0 = m0 * m0, s1 = m1 * m1;
#pragma unroll
  for (int o = 8; o > 0; o >>= 1) {
    s0 += __shfl_xor(s0, o, 32);
    s1 += __shfl_xor(s1, o, 32);
  }
  const float sq = s0 + s1;
  if (l32 < 16) {
    const float rn = 1.0f / fmaxf(sqrtf(sq), 1e-12f);
    float2 o2; o2.x = m0 * rn; o2.y = m1 * rn;
    *(float2*)(P1N + ((size_t)m * 64 + a) * 32 + 2 * l32) = o2;
  } else {
    float2 o2; o2.x = m0; o2.y = m1;
    *(float2*)(V1 + ((size_t)m * 64 + a) * 32 + 2 * (l32 - 16)) = o2;
  }
}

// ---------------------------------------------------------------------------
// Kernel C1: per-pixel l2norm(point0), sim vs 64 anchors, sigmoid, argmax.
// NOTE: argmax MUST compare post-sigmoid values (strict >, first-index wins):
// sigmoid compresses, so distinct pre-activations can round to the same f32
// sigmoid value — the reference tie-breaks on the rounded values. Comparing
// pre-activation z flips those ties (R2 failure, absmax 1.5e-2).
// ---------------------------------------------------------------------------
__global__ __launch_bounds__(256) void sim_argmax(
    const float* __restrict__ XP, const float* __restrict__ P1N,
    const float* __restrict__ alpha, const float* __restrict__ beta,
    float* __restrict__ SV, int* __restrict__ IDX) {
  const int m = blockIdx.x, chunk = blockIdx.y;
  const int n = m >> 3, h = m & 7;
  __shared__ float P1[64][32];
  const int tid = threadIdx.x;
  {
    const float4* src = (const float4*)(P1N + (size_t)m * 2048);
    float4* dst = (float4*)&P1[0][0];
    dst[tid] = src[tid];
    dst[tid + 256] = src[tid + 256];
  }
  __syncthreads();
  const float al = alpha[0], be = beta[0];

  const int p0 = chunk * 256 + tid;
  const int p1 = p0 + 2048;
  const float* row0 = XP + ((size_t)n * NPIX + p0) * DIM2 + h * 64;
  const float* row1 = XP + ((size_t)n * NPIX + p1) * DIM2 + h * 64;

  float v0[32], v1[32];
#pragma unroll
  for (int q = 0; q < 8; ++q) {
    float4 t0 = ((const float4*)row0)[q];
    float4 t1 = ((const float4*)row1)[q];
    v0[q * 4 + 0] = t0.x; v0[q * 4 + 1] = t0.y; v0[q * 4 + 2] = t0.z; v0[q * 4 + 3] = t0.w;
    v1[q * 4 + 0] = t1.x; v1[q * 4 + 1] = t1.y; v1[q * 4 + 2] = t1.z; v1[q * 4 + 3] = t1.w;
  }
  float ss0 = 0.f, ss1 = 0.f;
#pragma unroll
  for (int d = 0; d < 32; ++d) { ss0 += v0[d] * v0[d]; ss1 += v1[d] * v1[d]; }
  const float rn0 = 1.0f / fmaxf(sqrtf(ss0), 1e-12f);
  const float rn1 = 1.0f / fmaxf(sqrtf(ss1), 1e-12f);
#pragma unroll
  for (int d = 0; d < 32; ++d) { v0[d] *= rn0; v1[d] *= rn1; }

  float best0 = -1.f, best1 = -1.f;
  int bi0 = 0, bi1 = 0;
  for (int a = 0; a < 64; ++a) {
    float d0a = 0.f, d0b = 0.f, d1a = 0.f, d1b = 0.f;
#pragma unroll
    for (int d = 0; d < 16; ++d) {
      const float wa = P1[a][2 * d], wb = P1[a][2 * d + 1];
      d0a = fmaf(v0[2 * d], wa, d0a);
      d0b = fmaf(v0[2 * d + 1], wb, d0b);
      d1a = fmaf(v1[2 * d], wa, d1a);
      d1b = fmaf(v1[2 * d + 1], wb, d1b);
    }
    const float t0 = al * (d0a + d0b) + be;
    const float t1 = al * (d1a + d1b) + be;
    const float s0 = 1.0f / (1.0f + expf(-t0));
    const float s1 = 1.0f / (1.0f + expf(-t1));
    if (s0 > best0) { best0 = s0; bi0 = a; }
    if (s1 > best1) { best1 = s1; bi1 = a; }
  }
  SV[(size_t)m * NPIX + p0] = best0;
  IDX[(size_t)m * NPIX + p0] = bi0;
  SV[(size_t)m * NPIX + p1] = best1;
  IDX[(size_t)m * NPIX + p1] = bi1;
}

// ---------------------------------------------------------------------------
// Kernel C2a: partial scatter. grid (128 m, 4 seg), 256 threads = 8 groups x
// 32 lanes; group handles 128 consecutive pixels. Private LDS accumulators
// stride-65 (conflict-free). Run-length compression. Deterministic.
// R10: loads batched 4-wide (sv float4 / id int4, group-uniform broadcast;
// 4 scalar vv) to break the 128-iteration latency chain. Processing order
// unchanged -> bit-identical accumulation.
// ---------------------------------------------------------------------------
#define NSEG 4
__global__ __launch_bounds__(256) void scatter_partial(
    const float* __restrict__ XP, const float* __restrict__ SV,
    const int* __restrict__ IDX, float* __restrict__ PART) {
  const int m = blockIdx.x, seg = blockIdx.y;
  const int n = m >> 3, h = m & 7;
  __shared__ float agg[8][32][65];
  __shared__ float ssum[8][64];
  const int tid = threadIdx.x;
  const int g = tid >> 5, d = tid & 31;

  for (int e = tid; e < 8 * 32 * 65; e += 256) ((float*)agg)[e] = 0.f;
  for (int e = tid; e < 8 * 64; e += 256) ((float*)ssum)[e] = 0.f;
  __syncthreads();

  const size_t svbase = (size_t)m * NPIX;
  const int pbase = seg * 1024 + g * 128;
  int lastid = -1;
  float acc = 0.f, accS = 0.f;
  for (int i0 = 0; i0 < 128; i0 += 4) {
    const int p = pbase + i0;
    const float4 sv4 = *(const float4*)(SV + svbase + p);
    const int4 id4 = *(const int4*)(IDX + svbase + p);
    float vv4[4];
#pragma unroll
    for (int j = 0; j < 4; ++j)
      vv4[j] = XP[((size_t)n * NPIX + p + j) * DIM2 + h * 64 + 32 + d];
#pragma unroll
    for (int j = 0; j < 4; ++j) {
      const float sv = (&sv4.x)[j];
      const int id = (&id4.x)[j];
      if (id != lastid) {
        if (lastid >= 0) {
          agg[g][d][lastid] += acc;
          if (d == 0) ssum[g][lastid] += accS;
        }
        lastid = id; acc = 0.f; accS = 0.f;
      }
      acc = fmaf(vv4[j], sv, acc);
      accS += sv;
    }
  }
  if (lastid >= 0) {
    agg[g][d][lastid] += acc;
    if (d == 0) ssum[g][lastid] += accS;
  }
  __syncthreads();

  float* P = PART + (size_t)(m * NSEG + seg) * 2112;
  for (int e = tid; e < 2048; e += 256) {
    const int dd = e >> 6, aa = e & 63;
    float s = 0.f;
#pragma unroll
    for (int gg = 0; gg < 8; ++gg) s += agg[gg][dd][aa];
    P[e] = s;
  }
  if (tid < 64) {
    float s = 0.f;
#pragma unroll
    for (int gg = 0; gg < 8; ++gg) s += ssum[gg][tid];
    P[2048 + tid] = s;
  }
}

// ---------------------------------------------------------------------------
// Kernel C2b: reduce partials, add value1, divide, project through W_out.
// ---------------------------------------------------------------------------
__global__ __launch_bounds__(256) void reduce_proj(
    const float* __restrict__ PART, const float* __restrict__ V1,
    const float* __restrict__ Wout, float* __restrict__ PA) {
  const int m = blockIdx.x;
  const int h = m & 7;
  __shared__ float aggF[64][33];
  __shared__ float ssumF[64];
  const int tid = threadIdx.x;
  const float* P = PART + (size_t)m * NSEG * 2112;

  if (tid < 64) {
    float s = 0.f;
#pragma unroll
    for (int seg = 0; seg < NSEG; ++seg) s += P[seg * 2112 + 2048 + tid];
    ssumF[tid] = s + 1.0f;
  }
  __syncthreads();

  for (int e = tid; e < 2048; e += 256) {
    const int dd = e >> 6, aa = e & 63;
    float s = 0.f;
#pragma unroll
    for (int seg = 0; seg < NSEG; ++seg) s += P[seg * 2112 + e];
    s += V1[((size_t)m * 64 + aa) * 32 + dd];
    aggF[aa][dd] = s / ssumF[aa];
  }
  __syncthreads();

  float w[32];
  const float* wrow = Wout + (size_t)tid * 256 + h * 32;
#pragma unroll
  for (int q = 0; q < 8; ++q) {
    const float4 t = ((const float4*)wrow)[q];
    w[q * 4 + 0] = t.x; w[q * 4 + 1] = t.y; w[q * 4 + 2] = t.z; w[q * 4 + 3] = t.w;
  }
  for (int aa = 0; aa < 64; ++aa) {
    float s0 = 0.f, s1 = 0.f;
#pragma unroll
    for (int d2 = 0; d2 < 16; ++d2) {
      s0 = fmaf(w[2 * d2], aggF[aa][2 * d2], s0);
      s1 = fmaf(w[2 * d2 + 1], aggF[aa][2 * d2 + 1], s1);
    }
    PA[((size_t)m * 64 + aa) * 256 + tid] = s0 + s1;
  }
}

// ---------------------------------------------------------------------------
// Kernel E: out[p][o] = b_out[o] + sum_h sv_h * PA[m_h][idx_h][o]
// ---------------------------------------------------------------------------
__global__ __launch_bounds__(256) void out_assemble(
    const float* __restrict__ PA, const float* __restrict__ SV,
    const int* __restrict__ IDX, const float* __restrict__ bout,
    float* __restrict__ OUT) {
  const int tid = threadIdx.x;
  const int lp = tid >> 6, lane = tid & 63;
  const size_t p = (size_t)blockIdx.x * 4 + lp;
  const int n = (int)(p >> 12);
  const int pp = (int)(p & 4095);
  float4 acc = ((const float4*)bout)[lane];
#pragma unroll
  for (int h = 0; h < 8; ++h) {
    const int m = n * 8 + h;
    const float sv = SV[(size_t)m * NPIX + pp];
    const int id = IDX[(size_t)m * NPIX + pp];
    const float4 pa = ((const float4*)(PA + ((size_t)m * 64 + id) * 256))[lane];
    acc.x = fmaf(sv, pa.x, acc.x);
    acc.y = fmaf(sv, pa.y, acc.y);
    acc.z = fmaf(sv, pa.z, acc.z);
    acc.w = fmaf(sv, pa.w, acc.w);
  }
  ((float4*)OUT)[p * 64 + lane] = acc;
}

// ---------------------------------------------------------------------------
extern "C" void kernel_launch(void* const* d_in, const int* in_sizes, int n_in,
                              void* d_out, int out_size, void* d_ws, size_t ws_size,
                              hipStream_t stream) {
  const float* x     = (const float*)d_in[0];
  const float* Wp    = (const float*)d_in[1];
  const float* bp    = (const float*)d_in[2];
  const float* Wo    = (const float*)d_in[3];
  const float* bo    = (const float*)d_in[4];
  const float* alpha = (const float*)d_in[5];
  const float* beta  = (const float*)d_in[6];
  float* out = (float*)d_out;

  char* ws = (char*)d_ws;
  float* XP   = (float*)(ws);                          // 65536*512*4   = 134217728
  float* P1N  = (float*)(ws + 134217728u);             // 128*64*32*4   = 1048576
  float* V1   = (float*)(ws + 135266304u);             // 1048576
  float* SVv  = (float*)(ws + 136314880u);             // 128*4096*4    = 2097152
  int*   IDX  = (int*)  (ws + 138412032u);             // 2097152
  float* PA   = (float*)(ws + 140509184u);             // 128*64*256*4  = 8388608
  float* PART = (float*)(ws + 148897792u);             // 128*4*2112*4  = 4325376
  (void)in_sizes; (void)n_in; (void)out_size; (void)ws_size;

  proj_point     <<<dim3(512, 2), 512, 0, stream>>>(x, Wp, bp, XP);
  proj_value     <<<dim3(512, 2), 256, 0, stream>>>(x, Wp, bp, XP);
  pool_norm      <<<dim3(16, 64), 256, 0, stream>>>(XP, P1N, V1);
  sim_argmax     <<<dim3(128, 8), 256, 0, stream>>>(XP, P1N, alpha, beta, SVv, IDX);
  scatter_partial<<<dim3(128, NSEG), 256, 0, stream>>>(XP, SVv, IDX, PART);
  reduce_proj    <<<128, 256, 0, stream>>>(PART, V1, Wo, PA);
  out_assemble   <<<16384, 256, 0, stream>>>(PA, SVv, IDX, bo, out);
}

// Round 11
// 323.102 us; speedup vs baseline: 1.0610x; 1.0610x over previous
//
#include <hip/hip_runtime.h>
#include <float.h>
#include <math.h>

// SelfContextCluster: N=16, H=W=64, DIM=256, HEADS=8, HD=32, ANCH=8 (64 anchors)
// m = 128 maps (n*8+head). Channel layout of xp row (512): head*64 + c,
// c<32 = point, c>=32 = value.
//
// Structure (R9, validated): XP produced by TWO kernels split by consumer
// precision. Point cols: sequential-fmaf fp32 GEMM (argmax path needs
// fp32-class XP; MFMA split-bf16 flipped argmaxes in R7/R8). Value cols:
// 3-term split-bf16 MFMA (tolerant linear path, 25x margin).
// R11: proj_point reverted to R9 single-buffer (dbuf regressed 3/3 times:
// R5 spill, R10 occupancy 36->21% via 64KB LDS + VGPR 92; implicit wave
// overlap already covers staging latency on this structure). Tail keeps
// R10's batched scatter + float2 pool (worth ~30us combined).

#define NPIX   4096     // 64*64
#define NIMG   16
#define TOTPIX 65536
#define DIM2   512

typedef __attribute__((ext_vector_type(8))) short bf16x8;
typedef __attribute__((ext_vector_type(4))) float f32x4;

// ---------------------------------------------------------------------------
// Kernel A1: point-channel fp32 GEMM. M=65536, Npt=256, K=256.
// BM=BN=128, BK=32, 512 threads, 8x4 micro-tile. Single-buffered,
// 2 barriers/K-step (R9 verbatim; 112us, VGPR 52, no spill, passed).
// ---------------------------------------------------------------------------
#define BM 128
#define BN 128
#define BK 32

__global__ __launch_bounds__(512, 2) void proj_point(
    const float* __restrict__ X, const float* __restrict__ W,
    const float* __restrict__ bias, float* __restrict__ XP) {
  __shared__ float As[BK][BM];
  __shared__ float Bs[BK][BN];
  const int tid = threadIdx.x;
  const int M0 = blockIdx.x * BM, C0 = blockIdx.y * BN;   // C0: point-col space
  const int tm = tid >> 5, tn = tid & 31;      // 16 x 32 thread grid

  const int r = tid & 127;
  const int kq = (tid >> 7) << 3;              // 0,8,16,24

  const int pcr = C0 + r;                       // point-col of staged W row
  const float* Xa = X + (size_t)(M0 + r) * 256 + kq;
  const float* Wb = W + (size_t)((pcr >> 5) * 64 + (pcr & 31)) * 256 + kq;

  float4 xa0, xa1, wb0, wb1;

#define LOADT(ko)                                                      \
  do {                                                                 \
    xa0 = *(const float4*)(Xa + (ko));                                 \
    xa1 = *(const float4*)(Xa + (ko) + 4);                             \
    wb0 = *(const float4*)(Wb + (ko));                                 \
    wb1 = *(const float4*)(Wb + (ko) + 4);                             \
  } while (0)

  float acc[8][4];
#pragma unroll
  for (int i = 0; i < 8; ++i)
#pragma unroll
    for (int j = 0; j < 4; ++j) acc[i][j] = 0.f;

  LOADT(0);

  for (int k0 = 0; k0 < 256; k0 += BK) {
    __syncthreads();
#pragma unroll
    for (int j = 0; j < 4; ++j) {
      As[kq + j][r]     = (&xa0.x)[j];
      As[kq + 4 + j][r] = (&xa1.x)[j];
      Bs[kq + j][r]     = (&wb0.x)[j];
      Bs[kq + 4 + j][r] = (&wb1.x)[j];
    }
    __syncthreads();
    if (k0 + BK < 256) LOADT(k0 + BK);
#pragma unroll
    for (int kk = 0; kk < BK; ++kk) {
      float a[8], b[4];
      *(float4*)&a[0] = *(const float4*)&As[kk][tm * 8];
      *(float4*)&a[4] = *(const float4*)&As[kk][tm * 8 + 4];
      *(float4*)&b[0] = *(const float4*)&Bs[kk][tn * 4];
#pragma unroll
      for (int i = 0; i < 8; ++i)
#pragma unroll
        for (int j = 0; j < 4; ++j)
          acc[i][j] = fmaf(a[i], b[j], acc[i][j]);
    }
  }

  // point-col c = C0 + tn*4 (4-aligned within a 32-chunk) -> phys contiguous
  const int c = C0 + tn * 4;
  const int pcol = (c >> 5) * 64 + (c & 31);
  const float4 bq = *(const float4*)(bias + pcol);
#pragma unroll
  for (int i = 0; i < 8; ++i) {
    const size_t row = (size_t)(M0 + tm * 8 + i) * DIM2 + pcol;
    float4 o;
    o.x = acc[i][0] + bq.x; o.y = acc[i][1] + bq.y;
    o.z = acc[i][2] + bq.z; o.w = acc[i][3] + bq.w;
    *(float4*)(XP + row) = o;
  }
}

// ---------------------------------------------------------------------------
// Kernel A2: value-channel 3-term split-bf16 MFMA GEMM (R9 verbatim).
// ---------------------------------------------------------------------------
__device__ __forceinline__ void split2(float x, unsigned short& h1,
                                       unsigned short& h2) {
  unsigned u1 = __float_as_uint(x);
  h1 = (unsigned short)(u1 >> 16);
  float r1 = x - __uint_as_float(u1 & 0xFFFF0000u);
  h2 = (unsigned short)(__float_as_uint(r1) >> 16);
}

__global__ __launch_bounds__(256, 2) void proj_value(
    const float* __restrict__ X, const float* __restrict__ W,
    const float* __restrict__ bias, float* __restrict__ XP) {
  __shared__ unsigned char lds[4 * 8192];   // A1,A2,B1,B2 planes
  const int tid = threadIdx.x;
  const int M0 = blockIdx.x * 128;
  const int V0 = blockIdx.y * 128;          // value-col space (0 or 128)

  const int w = tid >> 6, l = tid & 63;
  const int wm = w >> 1, wn = w & 1;

  const int jj = tid & 7;
  const int rsub = tid >> 3;

  const float* Xbase = X + (size_t)M0 * 256;

  float4 ra[4], rb[4];
#define GLOADV(kofs)                                                          \
  do {                                                                        \
    _Pragma("unroll") for (int i = 0; i < 4; ++i) {                           \
      ra[i] = *(const float4*)(Xbase + (size_t)(i * 32 + rsub) * 256 + (kofs) + jj * 4); \
      rb[i] = *(const float4*)(W + (size_t)((((V0 >> 5) + i) * 64) + 32 + rsub) * 256 + (kofs) + jj * 4); \
    }                                                                         \
  } while (0)

  f32x4 acc[4][4] = {};

  const int fr = l & 15, kg = l >> 4;
  const int chunk = kg << 4;                 // 16B chunk within 64B row

  GLOADV(0);

  for (int s = 0; s < 8; ++s) {
    __syncthreads();
#pragma unroll
    for (int i = 0; i < 4; ++i) {
      const int row = i * 32 + rsub;
      const int off = row * 64 + jj * 8;
      unsigned short a1[4], a2[4], b1[4], b2[4];
#pragma unroll
      for (int e = 0; e < 4; ++e) {
        split2(((const float*)&ra[i])[e], a1[e], a2[e]);
        split2(((const float*)&rb[i])[e], b1[e], b2[e]);
      }
#define PK2(arr) make_uint2((unsigned)(arr)[0] | ((unsigned)(arr)[1] << 16),  \
                            (unsigned)(arr)[2] | ((unsigned)(arr)[3] << 16))
      *(uint2*)(lds + 0 * 8192 + off) = PK2(a1);
      *(uint2*)(lds + 1 * 8192 + off) = PK2(a2);
      *(uint2*)(lds + 2 * 8192 + off) = PK2(b1);
      *(uint2*)(lds + 3 * 8192 + off) = PK2(b2);
#undef PK2
    }
    __syncthreads();
    if (s < 7) GLOADV((s + 1) * 32);

    bf16x8 af[4][2];
#pragma unroll
    for (int mi = 0; mi < 4; ++mi) {
      const int base = (wm * 64 + mi * 16 + fr) * 64 + chunk;
      af[mi][0] = *(const bf16x8*)(lds + 0 * 8192 + base);
      af[mi][1] = *(const bf16x8*)(lds + 1 * 8192 + base);
    }
#pragma unroll
    for (int ni = 0; ni < 4; ++ni) {
      const int base = (wn * 64 + ni * 16 + fr) * 64 + chunk;
      const bf16x8 b1 = *(const bf16x8*)(lds + 2 * 8192 + base);
      const bf16x8 b2 = *(const bf16x8*)(lds + 3 * 8192 + base);
#pragma unroll
      for (int mi = 0; mi < 4; ++mi) {
        f32x4 c = acc[mi][ni];
        c = __builtin_amdgcn_mfma_f32_16x16x32_bf16(af[mi][0], b1, c, 0, 0, 0);
        c = __builtin_amdgcn_mfma_f32_16x16x32_bf16(af[mi][0], b2, c, 0, 0, 0);
        c = __builtin_amdgcn_mfma_f32_16x16x32_bf16(af[mi][1], b1, c, 0, 0, 0);
        acc[mi][ni] = c;
      }
    }
  }

  // epilogue: value-col vc = V0 + wn*64 + ni*16 + fr -> phys col
  const int orow0 = M0 + wm * 64 + (l >> 4) * 4;
#pragma unroll
  for (int ni = 0; ni < 4; ++ni) {
    const int vc = V0 + wn * 64 + ni * 16 + fr;
    const int pcol = (vc >> 5) * 64 + 32 + (vc & 31);
    const float bv = bias[pcol];
#pragma unroll
    for (int mi = 0; mi < 4; ++mi)
#pragma unroll
      for (int j = 0; j < 4; ++j)
        XP[(size_t)(orow0 + mi * 16 + j) * DIM2 + pcol] = acc[mi][ni][j] + bv;
  }
}

// ---------------------------------------------------------------------------
// Kernel B: 8x8 max-pool + l2-normalize point1, store value1.
// Thread t handles channel PAIR (2t, 2t+1) via float2 loads. Norm reduction
// reproduces the original 5-level butterfly bit-exactly (parity-split tree,
// R10 verified). Max is order-invariant.
// ---------------------------------------------------------------------------
__global__ __launch_bounds__(256) void pool_norm(
    const float* __restrict__ XP, float* __restrict__ P1N,
    float* __restrict__ V1) {
  const int n = blockIdx.x, a = blockIdx.y;
  const int ay = a >> 3, ax = a & 7;
  const int tid = threadIdx.x;
  const size_t base = ((size_t)n * NPIX + (size_t)(ay * 8) * 64 + ax * 8) * DIM2;
  const int c0 = tid * 2;
  float m0 = -FLT_MAX, m1 = -FLT_MAX;
#pragma unroll
  for (int iy = 0; iy < 8; ++iy) {
    const float* rowp = XP + base + (size_t)iy * 64 * DIM2;
#pragma unroll
    for (int ix = 0; ix < 8; ++ix) {
      const float2 v = *(const float2*)(rowp + (size_t)ix * DIM2 + c0);
      m0 = fmaxf(m0, v.x);
      m1 = fmaxf(m1, v.y);
    }
  }
  const int m = n * 8 + (tid >> 5);
  const int l32 = tid & 31;
  float s0 = m0 * m0, s1 = m1 * m1;
#pragma unroll
  for (int o = 8; o > 0; o >>= 1) {
    s0 += __shfl_xor(s0, o, 32);
    s1 += __shfl_xor(s1, o, 32);
  }
  const float sq = s0 + s1;
  if (l32 < 16) {
    const float rn = 1.0f / fmaxf(sqrtf(sq), 1e-12f);
    float2 o2; o2.x = m0 * rn; o2.y = m1 * rn;
    *(float2*)(P1N + ((size_t)m * 64 + a) * 32 + 2 * l32) = o2;
  } else {
    float2 o2; o2.x = m0; o2.y = m1;
    *(float2*)(V1 + ((size_t)m * 64 + a) * 32 + 2 * (l32 - 16)) = o2;
  }
}

// ---------------------------------------------------------------------------
// Kernel C1: per-pixel l2norm(point0), sim vs 64 anchors, sigmoid, argmax.
// NOTE: argmax MUST compare post-sigmoid values (strict >, first-index wins):
// sigmoid compresses, so distinct pre-activations can round to the same f32
// sigmoid value — the reference tie-breaks on the rounded values. Comparing
// pre-activation z flips those ties (R2 failure, absmax 1.5e-2).
// ---------------------------------------------------------------------------
__global__ __launch_bounds__(256) void sim_argmax(
    const float* __restrict__ XP, const float* __restrict__ P1N,
    const float* __restrict__ alpha, const float* __restrict__ beta,
    float* __restrict__ SV, int* __restrict__ IDX) {
  const int m = blockIdx.x, chunk = blockIdx.y;
  const int n = m >> 3, h = m & 7;
  __shared__ float P1[64][32];
  const int tid = threadIdx.x;
  {
    const float4* src = (const float4*)(P1N + (size_t)m * 2048);
    float4* dst = (float4*)&P1[0][0];
    dst[tid] = src[tid];
    dst[tid + 256] = src[tid + 256];
  }
  __syncthreads();
  const float al = alpha[0], be = beta[0];

  const int p0 = chunk * 256 + tid;
  const int p1 = p0 + 2048;
  const float* row0 = XP + ((size_t)n * NPIX + p0) * DIM2 + h * 64;
  const float* row1 = XP + ((size_t)n * NPIX + p1) * DIM2 + h * 64;

  float v0[32], v1[32];
#pragma unroll
  for (int q = 0; q < 8; ++q) {
    float4 t0 = ((const float4*)row0)[q];
    float4 t1 = ((const float4*)row1)[q];
    v0[q * 4 + 0] = t0.x; v0[q * 4 + 1] = t0.y; v0[q * 4 + 2] = t0.z; v0[q * 4 + 3] = t0.w;
    v1[q * 4 + 0] = t1.x; v1[q * 4 + 1] = t1.y; v1[q * 4 + 2] = t1.z; v1[q * 4 + 3] = t1.w;
  }
  float ss0 = 0.f, ss1 = 0.f;
#pragma unroll
  for (int d = 0; d < 32; ++d) { ss0 += v0[d] * v0[d]; ss1 += v1[d] * v1[d]; }
  const float rn0 = 1.0f / fmaxf(sqrtf(ss0), 1e-12f);
  const float rn1 = 1.0f / fmaxf(sqrtf(ss1), 1e-12f);
#pragma unroll
  for (int d = 0; d < 32; ++d) { v0[d] *= rn0; v1[d] *= rn1; }

  float best0 = -1.f, best1 = -1.f;
  int bi0 = 0, bi1 = 0;
  for (int a = 0; a < 64; ++a) {
    float d0a = 0.f, d0b = 0.f, d1a = 0.f, d1b = 0.f;
#pragma unroll
    for (int d = 0; d < 16; ++d) {
      const float wa = P1[a][2 * d], wb = P1[a][2 * d + 1];
      d0a = fmaf(v0[2 * d], wa, d0a);
      d0b = fmaf(v0[2 * d + 1], wb, d0b);
      d1a = fmaf(v1[2 * d], wa, d1a);
      d1b = fmaf(v1[2 * d + 1], wb, d1b);
    }
    const float t0 = al * (d0a + d0b) + be;
    const float t1 = al * (d1a + d1b) + be;
    const float s0 = 1.0f / (1.0f + expf(-t0));
    const float s1 = 1.0f / (1.0f + expf(-t1));
    if (s0 > best0) { best0 = s0; bi0 = a; }
    if (s1 > best1) { best1 = s1; bi1 = a; }
  }
  SV[(size_t)m * NPIX + p0] = best0;
  IDX[(size_t)m * NPIX + p0] = bi0;
  SV[(size_t)m * NPIX + p1] = best1;
  IDX[(size_t)m * NPIX + p1] = bi1;
}

// ---------------------------------------------------------------------------
// Kernel C2a: partial scatter. grid (128 m, 4 seg), 256 threads = 8 groups x
// 32 lanes; group handles 128 consecutive pixels. Private LDS accumulators
// stride-65 (conflict-free). Run-length compression; loads batched 4-wide
// (processing order unchanged -> bit-identical). Deterministic.
// ---------------------------------------------------------------------------
#define NSEG 4
__global__ __launch_bounds__(256) void scatter_partial(
    const float* __restrict__ XP, const float* __restrict__ SV,
    const int* __restrict__ IDX, float* __restrict__ PART) {
  const int m = blockIdx.x, seg = blockIdx.y;
  const int n = m >> 3, h = m & 7;
  __shared__ float agg[8][32][65];
  __shared__ float ssum[8][64];
  const int tid = threadIdx.x;
  const int g = tid >> 5, d = tid & 31;

  for (int e = tid; e < 8 * 32 * 65; e += 256) ((float*)agg)[e] = 0.f;
  for (int e = tid; e < 8 * 64; e += 256) ((float*)ssum)[e] = 0.f;
  __syncthreads();

  const size_t svbase = (size_t)m * NPIX;
  const int pbase = seg * 1024 + g * 128;
  int lastid = -1;
  float acc = 0.f, accS = 0.f;
  for (int i0 = 0; i0 < 128; i0 += 4) {
    const int p = pbase + i0;
    const float4 sv4 = *(const float4*)(SV + svbase + p);
    const int4 id4 = *(const int4*)(IDX + svbase + p);
    float vv4[4];
#pragma unroll
    for (int j = 0; j < 4; ++j)
      vv4[j] = XP[((size_t)n * NPIX + p + j) * DIM2 + h * 64 + 32 + d];
#pragma unroll
    for (int j = 0; j < 4; ++j) {
      const float sv = (&sv4.x)[j];
      const int id = (&id4.x)[j];
      if (id != lastid) {
        if (lastid >= 0) {
          agg[g][d][lastid] += acc;
          if (d == 0) ssum[g][lastid] += accS;
        }
        lastid = id; acc = 0.f; accS = 0.f;
      }
      acc = fmaf(vv4[j], sv, acc);
      accS += sv;
    }
  }
  if (lastid >= 0) {
    agg[g][d][lastid] += acc;
    if (d == 0) ssum[g][lastid] += accS;
  }
  __syncthreads();

  float* P = PART + (size_t)(m * NSEG + seg) * 2112;
  for (int e = tid; e < 2048; e += 256) {
    const int dd = e >> 6, aa = e & 63;
    float s = 0.f;
#pragma unroll
    for (int gg = 0; gg < 8; ++gg) s += agg[gg][dd][aa];
    P[e] = s;
  }
  if (tid < 64) {
    float s = 0.f;
#pragma unroll
    for (int gg = 0; gg < 8; ++gg) s += ssum[gg][tid];
    P[2048 + tid] = s;
  }
}

// ---------------------------------------------------------------------------
// Kernel C2b: reduce partials, add value1, divide, project through W_out.
// ---------------------------------------------------------------------------
__global__ __launch_bounds__(256) void reduce_proj(
    const float* __restrict__ PART, const float* __restrict__ V1,
    const float* __restrict__ Wout, float* __restrict__ PA) {
  const int m = blockIdx.x;
  const int h = m & 7;
  __shared__ float aggF[64][33];
  __shared__ float ssumF[64];
  const int tid = threadIdx.x;
  const float* P = PART + (size_t)m * NSEG * 2112;

  if (tid < 64) {
    float s = 0.f;
#pragma unroll
    for (int seg = 0; seg < NSEG; ++seg) s += P[seg * 2112 + 2048 + tid];
    ssumF[tid] = s + 1.0f;
  }
  __syncthreads();

  for (int e = tid; e < 2048; e += 256) {
    const int dd = e >> 6, aa = e & 63;
    float s = 0.f;
#pragma unroll
    for (int seg = 0; seg < NSEG; ++seg) s += P[seg * 2112 + e];
    s += V1[((size_t)m * 64 + aa) * 32 + dd];
    aggF[aa][dd] = s / ssumF[aa];
  }
  __syncthreads();

  float w[32];
  const float* wrow = Wout + (size_t)tid * 256 + h * 32;
#pragma unroll
  for (int q = 0; q < 8; ++q) {
    const float4 t = ((const float4*)wrow)[q];
    w[q * 4 + 0] = t.x; w[q * 4 + 1] = t.y; w[q * 4 + 2] = t.z; w[q * 4 + 3] = t.w;
  }
  for (int aa = 0; aa < 64; ++aa) {
    float s0 = 0.f, s1 = 0.f;
#pragma unroll
    for (int d2 = 0; d2 < 16; ++d2) {
      s0 = fmaf(w[2 * d2], aggF[aa][2 * d2], s0);
      s1 = fmaf(w[2 * d2 + 1], aggF[aa][2 * d2 + 1], s1);
    }
    PA[((size_t)m * 64 + aa) * 256 + tid] = s0 + s1;
  }
}

// ---------------------------------------------------------------------------
// Kernel E: out[p][o] = b_out[o] + sum_h sv_h * PA[m_h][idx_h][o]
// ---------------------------------------------------------------------------
__global__ __launch_bounds__(256) void out_assemble(
    const float* __restrict__ PA, const float* __restrict__ SV,
    const int* __restrict__ IDX, const float* __restrict__ bout,
    float* __restrict__ OUT) {
  const int tid = threadIdx.x;
  const int lp = tid >> 6, lane = tid & 63;
  const size_t p = (size_t)blockIdx.x * 4 + lp;
  const int n = (int)(p >> 12);
  const int pp = (int)(p & 4095);
  float4 acc = ((const float4*)bout)[lane];
#pragma unroll
  for (int h = 0; h < 8; ++h) {
    const int m = n * 8 + h;
    const float sv = SV[(size_t)m * NPIX + pp];
    const int id = IDX[(size_t)m * NPIX + pp];
    const float4 pa = ((const float4*)(PA + ((size_t)m * 64 + id) * 256))[lane];
    acc.x = fmaf(sv, pa.x, acc.x);
    acc.y = fmaf(sv, pa.y, acc.y);
    acc.z = fmaf(sv, pa.z, acc.z);
    acc.w = fmaf(sv, pa.w, acc.w);
  }
  ((float4*)OUT)[p * 64 + lane] = acc;
}

// ---------------------------------------------------------------------------
extern "C" void kernel_launch(void* const* d_in, const int* in_sizes, int n_in,
                              void* d_out, int out_size, void* d_ws, size_t ws_size,
                              hipStream_t stream) {
  const float* x     = (const float*)d_in[0];
  const float* Wp    = (const float*)d_in[1];
  const float* bp    = (const float*)d_in[2];
  const float* Wo    = (const float*)d_in[3];
  const float* bo    = (const float*)d_in[4];
  const float* alpha = (const float*)d_in[5];
  const float* beta  = (const float*)d_in[6];
  float* out = (float*)d_out;

  char* ws = (char*)d_ws;
  float* XP   = (float*)(ws);                          // 65536*512*4   = 134217728
  float* P1N  = (float*)(ws + 134217728u);             // 128*64*32*4   = 1048576
  float* V1   = (float*)(ws + 135266304u);             // 1048576
  float* SVv  = (float*)(ws + 136314880u);             // 128*4096*4    = 2097152
  int*   IDX  = (int*)  (ws + 138412032u);             // 2097152
  float* PA   = (float*)(ws + 140509184u);             // 128*64*256*4  = 8388608
  float* PART = (float*)(ws + 148897792u);             // 128*4*2112*4  = 4325376
  (void)in_sizes; (void)n_in; (void)out_size; (void)ws_size;

  proj_point     <<<dim3(512, 2), 512, 0, stream>>>(x, Wp, bp, XP);
  proj_value     <<<dim3(512, 2), 256, 0, stream>>>(x, Wp, bp, XP);
  pool_norm      <<<dim3(16, 64), 256, 0, stream>>>(XP, P1N, V1);
  sim_argmax     <<<dim3(128, 8), 256, 0, stream>>>(XP, P1N, alpha, beta, SVv, IDX);
  scatter_partial<<<dim3(128, NSEG), 256, 0, stream>>>(XP, SVv, IDX, PART);
  reduce_proj    <<<128, 256, 0, stream>>>(PART, V1, Wo, PA);
  out_assemble   <<<16384, 256, 0, stream>>>(PA, SVv, IDX, bo, out);
}